// Round 8
// baseline (12837.749 us; speedup 1.0000x reference)
//
#include <hip/hip_runtime.h>

#define VOCABN 401
#define EN 256
#define HN 768
#define H3N 2304
#define ON 3
#define BN 64
#define TN 1024

// 16 replicas x 16 WGs; each WG: 48 j's, k split 8 ways, 4 batches
#define NREP 16
#define WGPR 16
#define BPR  4
#define JPW  48
#define NTH  384

typedef _Float16 f16x2 __attribute__((ext_vector_type(2)));
typedef _Float16 f16x8 __attribute__((ext_vector_type(8)));
union F16x8 { f16x8 v; f16x2 p[4]; };

__device__ __forceinline__ float fdot2(f16x2 a, f16x2 b, float c) {
#if __has_builtin(__builtin_amdgcn_fdot2)
    return __builtin_amdgcn_fdot2(a, b, c, false);
#else
    return c + (float)a[0] * (float)b[0] + (float)a[1] * (float)b[1];
#endif
}

// sum over each aligned 8-lane group (butterfly, same tree as shfl_xor 1/2/4);
// pure VALU via DPP: quad_perm xor1, quad_perm xor2, row_half_mirror (8-lane mirror).
__device__ __forceinline__ float octet_sum(float x) {
    int v = __builtin_bit_cast(int, x);
    x += __builtin_bit_cast(float, __builtin_amdgcn_update_dpp(0, v, 0xB1, 0xF, 0xF, true));
    v = __builtin_bit_cast(int, x);
    x += __builtin_bit_cast(float, __builtin_amdgcn_update_dpp(0, v, 0x4E, 0xF, 0xF, true));
    v = __builtin_bit_cast(int, x);
    x += __builtin_bit_cast(float, __builtin_amdgcn_update_dpp(0, v, 0x141, 0xF, 0xF, true));
    return x;
}

// tagged u64 = two u32 words, each [31:16]=step tag, [15:0]=f16 h bits.
__device__ __forceinline__ unsigned long long ld_tagged(const unsigned long long* p, unsigned wt) {
    unsigned long long v = __hip_atomic_load(p, __ATOMIC_RELAXED, __HIP_MEMORY_SCOPE_AGENT);
    while (!((((unsigned)(v >> 16) & 0xffffu) == wt) & ((unsigned)(v >> 48) == wt)))
        v = __hip_atomic_load(p, __ATOMIC_RELAXED, __HIP_MEMORY_SCOPE_AGENT);
    return v;
}

// ---------------- K1: gtab[v][g] = dot(embed[v], W_ih[g]) + b_ih[g]  (w-stationary)
__global__ __launch_bounds__(256)
void k_build_gtab(const float* __restrict__ embed, const float* __restrict__ wih,
                  const float* __restrict__ bih, float* __restrict__ gtab) {
    const int g  = blockIdx.x * 64 + (threadIdx.x >> 2);
    const int ql = threadIdx.x & 3;
    const int v0 = blockIdx.y * 26;
    const int v1 = min(VOCABN, v0 + 26);
    float4 w[16];
    const float4* s4 = (const float4*)(wih + (size_t)g * EN + ql * 64);
#pragma unroll
    for (int i = 0; i < 16; ++i) w[i] = s4[i];
    const float bias = bih[g];
    for (int v = v0; v < v1; ++v) {
        const float4* e4 = (const float4*)(embed + (size_t)v * EN + ql * 64);
        float acc = 0.f;
#pragma unroll
        for (int i = 0; i < 16; ++i) {
            float4 e = e4[i];
            acc += w[i].x * e.x + w[i].y * e.y + w[i].z * e.z + w[i].w * e.w;
        }
        acc += __shfl_xor(acc, 1, 64);
        acc += __shfl_xor(acc, 2, 64);
        if (ql == 0) gtab[(size_t)v * H3N + g] = acc + bias;
    }
}

// ---------------- K2: persistent-weight recurrence; tag-in-data, single-poller gate.
// The data IS the sync: a producer's tagged word at tag t proves it issued its
// step-t stores, which (program order + its deposit barrier) proves its step-(t-1)
// loads completed -> overwrite of buf[(t+1)&1] is transitively safe.
// memset-0 == valid t=0 state (tag 0, h=0). Agent-scope relaxed atomics only.
__global__ __launch_bounds__(NTH, 1)
void k_rnn(const int* __restrict__ tokens, const float* __restrict__ whh,
           const float* __restrict__ gtab, const float* __restrict__ bhh,
           unsigned* __restrict__ hbuf, float* __restrict__ hout) {
    const int R   = blockIdx.x & (NREP - 1);
    const int wg  = blockIdx.x >> 4;
    const int tid = threadIdx.x;
    const int jl  = tid >> 3;
    const int q   = tid & 7;
    const int j   = wg * JPW + jl;

    __shared__ __align__(16) _Float16 hlds[32 * 112];   // [b*8+qslot][96 data + 16 pad]

    // ---- one-time: weight slice -> 36 statically-indexed f16x8 (rows j,768+j,1536+j; k-octile q)
    F16x8 w[3][12];
#pragma unroll
    for (int g = 0; g < 3; ++g) {
        const float4* s4 = (const float4*)(whh + (size_t)(g * HN + j) * HN + q * 96);
#pragma unroll
        for (int c = 0; c < 12; ++c) {
            float4 a = s4[2 * c], b4 = s4[2 * c + 1];
            F16x8 t;
            t.v[0] = (_Float16)a.x;  t.v[1] = (_Float16)a.y;
            t.v[2] = (_Float16)a.z;  t.v[3] = (_Float16)a.w;
            t.v[4] = (_Float16)b4.x; t.v[5] = (_Float16)b4.y;
            t.v[6] = (_Float16)b4.z; t.v[7] = (_Float16)b4.w;
            w[g][c] = t;
        }
    }

    const float bhr = bhh[j], bhz = bhh[HN + j], bhn = bhh[2 * HN + j];
    unsigned long long* hb2 = (unsigned long long*)(hbuf + (size_t)R * (2 * BPR * HN));
    // consumer deposit mapping: u64 idx k*384+tid -> batch k, j0 = 2*tid
    const int lq  = tid / 48;                 // q-slot of j0
    const int lo2 = 2 * tid - 96 * lq;        // j0 % 96
    float hprev = 0.f;

    for (int t = 0; t < TN; ++t) {
        // ---- x-gate prefetch (tokens via L1, gtab L2-resident); overlaps the gate
        float xr = 0.f, xz = 0.f, xn = 0.f;
        if (q < BPR) {
            const int tok = tokens[(size_t)(R * BPR + q) * TN + t];
            const float* g_ = gtab + (size_t)tok * H3N;
            xr = g_[j]; xz = g_[HN + j]; xn = g_[2 * HN + j];
        }
        // ---- gate: tid0 polls one sentinel u64 per producer WG until tags == t
        if (tid == 0) {
            const unsigned long long* sb = hb2 + (t & 1) * 1536;
            for (;;) {
                unsigned bad = 0;
#pragma unroll
                for (int wp = 0; wp < WGPR; ++wp) {
                    unsigned long long v = __hip_atomic_load(&sb[wp * 24],
                                            __ATOMIC_RELAXED, __HIP_MEMORY_SCOPE_AGENT);
                    bad |= (((unsigned)(v >> 16) & 0xffffu) ^ (unsigned)t)
                         | ((unsigned)(v >> 48) ^ (unsigned)t);
                }
                if (!bad) break;
                __builtin_amdgcn_s_sleep(1);
            }
        }
        __syncthreads();

        // ---- 4 tagged u64 loads (verify tag; retries rare) + LDS deposit
        {
            const unsigned long long* hin = hb2 + (t & 1) * 1536 + tid;
#pragma unroll
            for (int k = 0; k < BPR; ++k) {
                unsigned long long v = ld_tagged(hin + k * NTH, (unsigned)t);
                unsigned dep = (((unsigned)(v >> 32)) << 16) | ((unsigned)v & 0xffffu);
                *(unsigned*)(hlds + (k * 8 + lq) * 112 + lo2) = dep;
            }
        }
        __syncthreads();                      // all loads done + tile ready

        // ---- dot: c-outer, each weight register read once per step
        float ar[BPR], az[BPR], an[BPR];
#pragma unroll
        for (int b = 0; b < BPR; ++b) { ar[b] = 0.f; az[b] = 0.f; an[b] = 0.f; }
#pragma unroll
        for (int c = 0; c < 12; ++c) {
            const F16x8 w0 = w[0][c], w1 = w[1][c], w2 = w[2][c];
#pragma unroll
            for (int b = 0; b < BPR; ++b) {
                F16x8 hh; hh.v = *(const f16x8*)(hlds + (b * 8 + q) * 112 + c * 8);
#pragma unroll
                for (int p = 0; p < 4; ++p) {
                    ar[b] = fdot2(w0.p[p], hh.p[p], ar[b]);
                    az[b] = fdot2(w1.p[p], hh.p[p], az[b]);
                    an[b] = fdot2(w2.p[p], hh.p[p], an[b]);
                }
            }
        }
        // ---- reduce (DPP), gates, pack, pair, publish
#pragma unroll
        for (int b = 0; b < BPR; ++b) {
            const float sr = octet_sum(ar[b]);
            const float sz = octet_sum(az[b]);
            const float sn = octet_sum(an[b]);
            unsigned pk = 0;
            if (q == b) {
                const float r  = 1.f / (1.f + __expf(-(xr + sr + bhr)));
                const float z  = 1.f / (1.f + __expf(-(xz + sz + bhz)));
                const float nx = xn + r * (sn + bhn);
                const float n  = 1.f - 2.f / (__expf(2.f * nx) + 1.f);   // tanh
                hprev = (1.f - z) * n + z * hprev;
                pk = ((unsigned)(t + 1) << 16)
                   | (unsigned)__builtin_bit_cast(unsigned short, (_Float16)hprev);
            }
            const unsigned pk2 = __shfl_down(pk, 8, 64);   // neighbor jl+1, same q
            if (q == b) {
                if (t < TN - 1) {
                    if (!(jl & 1))
                        __hip_atomic_store(
                            &hb2[((t + 1) & 1) * 1536 + b * 384 + wg * 24 + (jl >> 1)],
                            (unsigned long long)pk | ((unsigned long long)pk2 << 32),
                            __ATOMIC_RELAXED, __HIP_MEMORY_SCOPE_AGENT);
                } else {
                    hout[(size_t)(R * BPR + b) * HN + j] = hprev;
                }
            }
        }
    }
}

// ---------------- K3: logits + log_softmax
__global__ void k_logits(const float* __restrict__ hfin, const float* __restrict__ wout,
                         const float* __restrict__ bout, float* __restrict__ lp) {
    const int b = blockIdx.x;
    const int o = threadIdx.x / 64;
    const int lane = threadIdx.x % 64;
    const float* hrow = hfin + (size_t)b * HN;
    const float* w = wout + (size_t)o * HN;
    float p = 0.f;
    for (int k = lane; k < HN; k += 64) p += hrow[k] * w[k];
    for (int off = 32; off > 0; off >>= 1) p += __shfl_down(p, off, 64);
    __shared__ float lg[ON];
    if (lane == 0) lg[o] = p + bout[o];
    __syncthreads();
    if (threadIdx.x == 0) {
        float m = fmaxf(lg[0], fmaxf(lg[1], lg[2]));
        float s = __expf(lg[0] - m) + __expf(lg[1] - m) + __expf(lg[2] - m);
        float ls = __logf(s);
        lp[b * ON + 0] = lg[0] - m - ls;
        lp[b * ON + 1] = lg[1] - m - ls;
        lp[b * ON + 2] = lg[2] - m - ls;
    }
}

extern "C" void kernel_launch(void* const* d_in, const int* in_sizes, int n_in,
                              void* d_out, int out_size, void* d_ws, size_t ws_size,
                              hipStream_t stream) {
    const int*   tokens = (const int*)d_in[0];
    // d_in[1] = hidden: reference zeroes it, ignored.
    const float* embed  = (const float*)d_in[2];
    const float* wih    = (const float*)d_in[3];
    const float* whh    = (const float*)d_in[4];
    const float* bih    = (const float*)d_in[5];
    const float* bhh    = (const float*)d_in[6];
    const float* wout   = (const float*)d_in[7];
    const float* bout   = (const float*)d_in[8];

    float* out = (float*)d_out;                  // [B*O logprobs][B*H h_final]
    char* ws = (char*)d_ws;
    const size_t GTAB_OFF = 0;                   // 401*2304*4 = 3,695,616
    const size_t HBUF_OFF = 3695616;             // 16*2*3072*4 = 393,216 (tagged u32)
    float*    gtab = (float*)(ws + GTAB_OFF);
    unsigned* hbuf = (unsigned*)(ws + HBUF_OFF);

    // tag protocol requires tag==0 / h==0 state on EVERY launch (graph-replayed)
    hipMemsetAsync(ws + HBUF_OFF, 0, 393216, stream);

    hipLaunchKernelGGL(k_build_gtab, dim3(H3N / 64, 16), dim3(256), 0, stream,
                       embed, wih, bih, gtab);
    hipLaunchKernelGGL(k_rnn, dim3(NREP * WGPR), dim3(NTH), 0, stream,
                       tokens, whh, gtab, bhh, hbuf, out + BN * ON);
    hipLaunchKernelGGL(k_logits, dim3(BN), dim3(192), 0, stream,
                       out + BN * ON, wout, bout, out);
}